// Round 12
// baseline (1247.829 us; speedup 1.0000x reference)
//
#include <hip/hip_runtime.h>
#include <hip/hip_fp16.h>
#include <hip/hip_cooperative_groups.h>

namespace cg = cooperative_groups;

typedef __attribute__((ext_vector_type(8))) short short8v;
typedef __attribute__((ext_vector_type(8))) _Float16 half8v;
typedef __attribute__((ext_vector_type(4))) float f32x4;

// ---------------- helpers ----------------
__device__ __forceinline__ float h2f_lo(unsigned u) {
    return __half2float(__ushort_as_half((unsigned short)(u & 0xffffu)));
}
__device__ __forceinline__ float h2f_hi(unsigned u) {
    return __half2float(__ushort_as_half((unsigned short)(u >> 16)));
}
__device__ __forceinline__ unsigned f2h_pack(float a, float b) {
    return (unsigned)__half_as_ushort(__float2half(a)) |
           ((unsigned)__half_as_ushort(__float2half(b)) << 16);
}
__device__ __forceinline__ unsigned packsplit_f16(float v) {
    unsigned short hs = __half_as_ushort(__float2half(v));
    float r = v - __half2float(__ushort_as_half(hs));
    unsigned short ls = __half_as_ushort(__float2half(r));
    return (((unsigned)hs) << 16) | (unsigned)ls;
}
__device__ __forceinline__ void unpack8(const uint4 u0, const uint4 u1,
                                        short8v& hi, short8v& lo) {
    unsigned av[8] = {u0.x, u0.y, u0.z, u0.w, u1.x, u1.y, u1.z, u1.w};
#pragma unroll
    for (int i = 0; i < 8; ++i) {
        hi[i] = (short)(av[i] >> 16);
        lo[i] = (short)(av[i] & 0xffffu);
    }
}
__device__ __forceinline__ int lower_bound(const int* __restrict__ a, int n, int v) {
    int lo = 0, hi = n;
    while (lo < hi) {
        int mid = (lo + hi) >> 1;
        if (a[mid] < v) lo = mid + 1; else hi = mid;
    }
    return lo;
}

// ================= shared device phase bodies =================

// GEMM: C[M,N] = A[M,K] @ W[K,N]; A fp16 [M][K]; WT f16-split packed [N][K].
// 64x64 tile, BK=32, 4 waves x 32x32; 2 MFMA per frag pair.
template<bool HAS_BIAS, bool RELU, bool SCALE>
__device__ void gemm_body(const __half* __restrict__ Ah, const unsigned* __restrict__ WTp,
                          const float* __restrict__ bias, const float* __restrict__ dscale,
                          __half* __restrict__ Cout, int M, int K, int N,
                          char* smem, int firstTile, int tileStride) {
    _Float16 (*Ash)[72]       = (_Float16(*)[72])smem;
    unsigned short (*Bsh)[72] = (unsigned short(*)[72])(smem + 9216);
    const int tid = threadIdx.x;
    const int lane = tid & 63, w = tid >> 6;
    const int wm = (w >> 1) * 32, wn = (w & 1) * 32;
    const int m_st = tid >> 2, kq = tid & 3;
    const int ntn = N >> 6;
    const int ntiles = ((M + 63) >> 6) * ntn;

    for (int t = firstTile; t < ntiles; t += tileStride) {
        const int bm = (t / ntn) * 64, bn = (t % ntn) * 64;
        f32x4 acc[2][2];
#pragma unroll
        for (int i = 0; i < 2; ++i)
#pragma unroll
            for (int j = 0; j < 2; ++j) acc[i][j] = (f32x4){0.f, 0.f, 0.f, 0.f};

        for (int k0 = 0; k0 < K; k0 += 32) {
            {
                int row = bm + m_st;
                uint4 u = {0, 0, 0, 0};
                if (row < M)
                    u = *reinterpret_cast<const uint4*>(&Ah[(size_t)row * K + k0 + kq * 8]);
                *reinterpret_cast<uint4*>(&Ash[m_st][kq * 8]) = u;
            }
            {
                int nrow = bn + m_st;
                const uint4* g = reinterpret_cast<const uint4*>(&WTp[(size_t)nrow * K + k0 + kq * 8]);
                uint4 u0 = g[0], u1 = g[1];
                short8v hi, lo;
                unpack8(u0, u1, hi, lo);
                *reinterpret_cast<short8v*>(&Bsh[m_st][kq * 8])      = hi;
                *reinterpret_cast<short8v*>(&Bsh[m_st][32 + kq * 8]) = lo;
            }
            __syncthreads();

            half8v a[2], bh[2], bl[2];
#pragma unroll
            for (int mi = 0; mi < 2; ++mi)
                a[mi] = *reinterpret_cast<const half8v*>(&Ash[wm + mi * 16 + (lane & 15)][(lane >> 4) * 8]);
#pragma unroll
            for (int ni = 0; ni < 2; ++ni) {
                const unsigned short* p = &Bsh[wn + ni * 16 + (lane & 15)][(lane >> 4) * 8];
                bh[ni] = *reinterpret_cast<const half8v*>(p);
                bl[ni] = *reinterpret_cast<const half8v*>(p + 32);
            }
#pragma unroll
            for (int mi = 0; mi < 2; ++mi)
#pragma unroll
                for (int ni = 0; ni < 2; ++ni) {
                    acc[mi][ni] = __builtin_amdgcn_mfma_f32_16x16x32_f16(a[mi], bh[ni], acc[mi][ni], 0, 0, 0);
                    acc[mi][ni] = __builtin_amdgcn_mfma_f32_16x16x32_f16(a[mi], bl[ni], acc[mi][ni], 0, 0, 0);
                }
            __syncthreads();
        }

        // epilogue: D row=(lane>>4)*4+j, col=lane&15 (verified C/D mapping)
#pragma unroll
        for (int mi = 0; mi < 2; ++mi)
#pragma unroll
            for (int ni = 0; ni < 2; ++ni) {
                int colg = bn + wn + ni * 16 + (lane & 15);
                int rowb = bm + wm + mi * 16 + ((lane >> 4) << 2);
                float bv = 0.f;
                if constexpr (HAS_BIAS) bv = bias[colg];
#pragma unroll
                for (int j = 0; j < 4; ++j) {
                    int row = rowb + j;
                    if (row < M) {
                        float v = acc[mi][ni][j] + bv;
                        if constexpr (RELU) v = fmaxf(v, 0.f);
                        if constexpr (SCALE) v *= dscale[row];
                        Cout[(size_t)row * N + colg] = __float2half(v);
                    }
                }
            }
    }
}

// Aggregate: out_i = dinv_i*(h'_i + sum_nbr h'_s) [+bias]; h' fp16; f32 accum, 4 banks.
template<int F, bool HAS_BIAS, bool F16OUT>
__device__ void agg_body(const __half* __restrict__ h, const float* __restrict__ bias,
                         const float* __restrict__ dinv, const int* __restrict__ rowoff,
                         const int* __restrict__ col, void* __restrict__ out, int n,
                         int firstWave, int waveStride) {
    constexpr int VEC = F / 64;
    const int lane = threadIdx.x & 63;

    for (int node = firstWave; node < n; node += waveStride) {
        float di = dinv[node];
        float acc[4][VEC];
#pragma unroll
        for (int b = 0; b < 4; ++b)
#pragma unroll
            for (int v = 0; v < VEC; ++v) acc[b][v] = 0.f;
        {
            const __half* ps = &h[(size_t)node * F + lane * VEC];
            if constexpr (VEC == 4) {
                uint2 u = *reinterpret_cast<const uint2*>(ps);
                acc[0][0] = h2f_lo(u.x); acc[0][1] = h2f_hi(u.x);
                acc[0][2] = h2f_lo(u.y); acc[0][3] = h2f_hi(u.y);
            } else if constexpr (VEC == 2) {
                unsigned u = *reinterpret_cast<const unsigned*>(ps);
                acc[0][0] = h2f_lo(u); acc[0][1] = h2f_hi(u);
            } else {
                acc[0][0] = __half2float(*ps);
            }
        }
        int e = rowoff[node], s1 = rowoff[node + 1];
        for (; e + 3 < s1; e += 4) {
            int s_0 = col[e], s_1 = col[e + 1], s_2 = col[e + 2], s_3 = col[e + 3];
            const __half* p0 = &h[(size_t)s_0 * F + lane * VEC];
            const __half* p1 = &h[(size_t)s_1 * F + lane * VEC];
            const __half* p2 = &h[(size_t)s_2 * F + lane * VEC];
            const __half* p3 = &h[(size_t)s_3 * F + lane * VEC];
            if constexpr (VEC == 4) {
                uint2 u0 = *reinterpret_cast<const uint2*>(p0);
                uint2 u1 = *reinterpret_cast<const uint2*>(p1);
                uint2 u2 = *reinterpret_cast<const uint2*>(p2);
                uint2 u3 = *reinterpret_cast<const uint2*>(p3);
                acc[0][0] += h2f_lo(u0.x); acc[0][1] += h2f_hi(u0.x);
                acc[0][2] += h2f_lo(u0.y); acc[0][3] += h2f_hi(u0.y);
                acc[1][0] += h2f_lo(u1.x); acc[1][1] += h2f_hi(u1.x);
                acc[1][2] += h2f_lo(u1.y); acc[1][3] += h2f_hi(u1.y);
                acc[2][0] += h2f_lo(u2.x); acc[2][1] += h2f_hi(u2.x);
                acc[2][2] += h2f_lo(u2.y); acc[2][3] += h2f_hi(u2.y);
                acc[3][0] += h2f_lo(u3.x); acc[3][1] += h2f_hi(u3.x);
                acc[3][2] += h2f_lo(u3.y); acc[3][3] += h2f_hi(u3.y);
            } else if constexpr (VEC == 2) {
                unsigned u0 = *reinterpret_cast<const unsigned*>(p0);
                unsigned u1 = *reinterpret_cast<const unsigned*>(p1);
                unsigned u2 = *reinterpret_cast<const unsigned*>(p2);
                unsigned u3 = *reinterpret_cast<const unsigned*>(p3);
                acc[0][0] += h2f_lo(u0); acc[0][1] += h2f_hi(u0);
                acc[1][0] += h2f_lo(u1); acc[1][1] += h2f_hi(u1);
                acc[2][0] += h2f_lo(u2); acc[2][1] += h2f_hi(u2);
                acc[3][0] += h2f_lo(u3); acc[3][1] += h2f_hi(u3);
            } else {
                acc[0][0] += __half2float(*p0); acc[1][0] += __half2float(*p1);
                acc[2][0] += __half2float(*p2); acc[3][0] += __half2float(*p3);
            }
        }
        for (; e < s1; ++e) {
            int s = col[e];
            const __half* ps = &h[(size_t)s * F + lane * VEC];
            if constexpr (VEC == 4) {
                uint2 u = *reinterpret_cast<const uint2*>(ps);
                acc[0][0] += h2f_lo(u.x); acc[0][1] += h2f_hi(u.x);
                acc[0][2] += h2f_lo(u.y); acc[0][3] += h2f_hi(u.y);
            } else if constexpr (VEC == 2) {
                unsigned u = *reinterpret_cast<const unsigned*>(ps);
                acc[0][0] += h2f_lo(u); acc[0][1] += h2f_hi(u);
            } else {
                acc[0][0] += __half2float(*ps);
            }
        }

        float r[VEC];
#pragma unroll
        for (int v = 0; v < VEC; ++v)
            r[v] = ((acc[0][v] + acc[1][v]) + (acc[2][v] + acc[3][v])) * di;
        if constexpr (HAS_BIAS) {
#pragma unroll
            for (int v = 0; v < VEC; ++v) r[v] += bias[lane * VEC + v];
        }

        if constexpr (F16OUT) {
            unsigned* po = (unsigned*)out;
            if constexpr (VEC == 4)
                *reinterpret_cast<uint2*>(&po[(size_t)node * (F / 2) + lane * 2]) =
                    make_uint2(f2h_pack(r[0], r[1]), f2h_pack(r[2], r[3]));
            else if constexpr (VEC == 2)
                po[(size_t)node * (F / 2) + lane] = f2h_pack(r[0], r[1]);
            else
                ((__half*)out)[(size_t)node * F + lane] = __float2half(r[0]);
        } else {
            float* fo = (float*)out;
#pragma unroll
            for (int v = 0; v < VEC; ++v)
                fo[(size_t)node * F + lane * VEC + v] = r[v];
        }
    }
}

// ================= cooperative mega-kernel =================

struct MegaArgs {
    const float* x; const int* src; const int* dst; const int* batch;
    const float* W1; const float* b1; const float* W2; const float* b2;
    const float* W3; const float* b3;
    float* out;
    int n, E;
    int* cnt; int* rowoff; int* cursor; int* col; int* blockSums;  // blockSums[1024]
    float* dinv;
    unsigned* W1T; unsigned* W2T; unsigned* W3T;
    __half* XPh; __half* A0; __half* H1; __half* A1; __half* P2; __half* T3;
    float* H3;
};

__global__ __launch_bounds__(256, 4)
void k_mega(MegaArgs a) {
    cg::grid_group grid = cg::this_grid();
    __shared__ __align__(16) char smem[18432];
    const int nb = gridDim.x;                 // runtime-sized (<= 1024, >= 80)
    const int gtid = blockIdx.x * 256 + threadIdx.x;
    const int gs = nb * 256;
    const int lane = threadIdx.x & 63, wv = threadIdx.x >> 6;

    // ---- Phase A: zero cnt + zero blockSums pad + split all W ----
    for (int e = gtid; e < a.n; e += gs) a.cnt[e] = 0;
    for (int e = gtid; e < 1024; e += gs) a.blockSums[e] = 0;
    for (int e = gtid; e < 128 * 256; e += gs) {
        int k = e >> 8, nn = e & 255;
        a.W1T[(size_t)nn * 128 + k] = packsplit_f16(a.W1[e]);
    }
    for (int e = gtid; e < 256 * 256; e += gs) {
        int k = e >> 8, nn = e & 255;
        a.W2T[(size_t)nn * 256 + k] = packsplit_f16(a.W2[e]);
    }
    for (int e = gtid; e < 256 * 64; e += gs) {
        int k = e >> 6, nn = e & 63;
        a.W3T[(size_t)nn * 256 + k] = packsplit_f16(a.W3[e]);
    }
    grid.sync();

    // ---- Phase B: in-degree count ----
    for (int e = gtid; e < a.E; e += gs) atomicAdd(&a.cnt[a.dst[e]], 1);
    grid.sync();

    // ---- Phase C1: per-block scan partials (1 elem/thread; requires gs >= n) ----
    int myCnt = (gtid < a.n) ? a.cnt[gtid] : 0;
    int incl = myCnt;
#pragma unroll
    for (int off = 1; off < 64; off <<= 1) {
        int u = __shfl_up(incl, off, 64);
        if (lane >= off) incl += u;
    }
    int myExclInBlock;
    {
        int* wsum = (int*)smem;
        if (lane == 63) wsum[wv] = incl;
        __syncthreads();
        int be = 0;
#pragma unroll
        for (int i = 0; i < 4; ++i) if (i < wv) be += wsum[i];
        myExclInBlock = be + incl - myCnt;
        if (threadIdx.x == 255) a.blockSums[blockIdx.x] = be + incl;  // block total
    }
    grid.sync();

    // ---- Phase C2: block 0 scans the (zero-padded) 1024 block sums ----
    if (blockIdx.x == 0) {
        int t = threadIdx.x;
        int v0 = a.blockSums[t * 4 + 0], v1 = a.blockSums[t * 4 + 1];
        int v2 = a.blockSums[t * 4 + 2], v3 = a.blockSums[t * 4 + 3];
        int s = v0 + v1 + v2 + v3;
        int incl2 = s;
#pragma unroll
        for (int off = 1; off < 64; off <<= 1) {
            int u = __shfl_up(incl2, off, 64);
            if (lane >= off) incl2 += u;
        }
        int* ws2 = (int*)smem;
        __syncthreads();
        if (lane == 63) ws2[wv] = incl2;
        __syncthreads();
        int be2 = 0;
#pragma unroll
        for (int i = 0; i < 4; ++i) if (i < wv) be2 += ws2[i];
        int excl2 = be2 + incl2 - s;
        a.blockSums[t * 4 + 0] = excl2;
        a.blockSums[t * 4 + 1] = excl2 + v0;
        a.blockSums[t * 4 + 2] = excl2 + v0 + v1;
        a.blockSums[t * 4 + 3] = excl2 + v0 + v1 + v2;
        if (t == 255) a.rowoff[a.n] = excl2 + s;  // grand total = E
    }
    grid.sync();

    // ---- Phase C3: write rowoff / cursor / dinv ----
    if (gtid < a.n) {
        int excl = a.blockSums[blockIdx.x] + myExclInBlock;
        a.rowoff[gtid] = excl;
        a.cursor[gtid] = excl;
        a.dinv[gtid]   = rsqrtf((float)(myCnt + 1));
    }
    grid.sync();

    // ---- Phase D: CSR fill + x prescale ----
    for (int e = gtid; e < a.E; e += gs) {
        int pos = atomicAdd(&a.cursor[a.dst[e]], 1);
        a.col[pos] = a.src[e];
    }
    {
        int t4 = a.n * 32;
        for (int i = gtid; i < t4; i += gs) {
            float4 v = reinterpret_cast<const float4*>(a.x)[i];
            float d = a.dinv[i >> 5];
            reinterpret_cast<uint2*>(a.XPh)[i] =
                make_uint2(f2h_pack(v.x * d, v.y * d), f2h_pack(v.z * d, v.w * d));
        }
    }
    grid.sync();

    const int gw = blockIdx.x * 4 + wv, nw = nb * 4;
    // ---- Layer 1 ----
    agg_body<128, false, true>(a.XPh, nullptr, a.dinv, a.rowoff, a.col, a.A0, a.n, gw, nw);
    grid.sync();
    gemm_body<true, true, true>(a.A0, a.W1T, a.b1, a.dinv, a.H1, a.n, 128, 256, smem, blockIdx.x, nb);
    grid.sync();
    // ---- Layer 2 ----
    agg_body<256, false, true>(a.H1, nullptr, a.dinv, a.rowoff, a.col, a.A1, a.n, gw, nw);
    grid.sync();
    gemm_body<true, true, false>(a.A1, a.W2T, a.b2, nullptr, a.P2, a.n, 256, 256, smem, blockIdx.x, nb);
    grid.sync();
    // ---- Layer 3 ----
    gemm_body<false, false, true>(a.P2, a.W3T, nullptr, a.dinv, a.T3, a.n, 256, 64, smem, blockIdx.x, nb);
    grid.sync();
    agg_body<64, true, false>(a.T3, a.b3, a.dinv, a.rowoff, a.col, a.H3, a.n, gw, nw);
    grid.sync();

    // ---- Pool ----
    if (blockIdx.x < 64) {
        int g = blockIdx.x;
        int t = threadIdx.x;
        int fgrp = t & 15, rgrp = t >> 4;
        int start = lower_bound(a.batch, a.n, g);
        int end   = lower_bound(a.batch, a.n, g + 1);
        float4 acc = make_float4(0.f, 0.f, 0.f, 0.f);
        for (int i = start + rgrp; i < end; i += 16) {
            float4 v = *reinterpret_cast<const float4*>(&a.H3[(size_t)i * 64 + fgrp * 4]);
            acc.x += v.x; acc.y += v.y; acc.z += v.z; acc.w += v.w;
        }
        float4* red = (float4*)smem;
        red[t] = acc;
        __syncthreads();
#pragma unroll
        for (int off = 8; off >= 1; off >>= 1) {
            if (rgrp < off) {
                float4 o = red[(rgrp + off) * 16 + fgrp];
                float4 m = red[t];
                m.x += o.x; m.y += o.y; m.z += o.z; m.w += o.w;
                red[t] = m;
            }
            __syncthreads();
        }
        if (rgrp == 0) {
            float denom = (float)max(end - start, 1);
            float4 m = red[fgrp];
            *reinterpret_cast<float4*>(&a.out[g * 64 + fgrp * 4]) =
                make_float4(m.x / denom, m.y / denom, m.z / denom, m.w / denom);
        }
    }
}

// ================= fallback multi-kernel path (proven round-10) =================

__global__ void k_count(const int* __restrict__ dst, int* __restrict__ cnt, int E) {
    int e = blockIdx.x * blockDim.x + threadIdx.x;
    if (e < E) atomicAdd(&cnt[dst[e]], 1);
}

#define SCAN_CHUNK 20
__global__ void k_scan(const int* __restrict__ cnt, int* __restrict__ rowoff,
                       int* __restrict__ cursor, float* __restrict__ dinv, int n) {
    __shared__ int wsum[16];
    int t = threadIdx.x;
    int base = t * SCAN_CHUNK;
    int vals[SCAN_CHUNK];
    int local = 0;
#pragma unroll
    for (int i = 0; i < SCAN_CHUNK; ++i) {
        int idx = base + i;
        vals[i] = (idx < n) ? cnt[idx] : 0;
        local += vals[i];
    }
    int lane = t & 63, wv = t >> 6;
    int incl = local;
#pragma unroll
    for (int off = 1; off < 64; off <<= 1) {
        int u = __shfl_up(incl, off, 64);
        if (lane >= off) incl += u;
    }
    if (lane == 63) wsum[wv] = incl;
    __syncthreads();
    if (t == 0) {
        int run = 0;
#pragma unroll
        for (int i = 0; i < 16; ++i) { int v = wsum[i]; wsum[i] = run; run += v; }
    }
    __syncthreads();
    int run = wsum[wv] + incl - local;
#pragma unroll
    for (int i = 0; i < SCAN_CHUNK; ++i) {
        int idx = base + i;
        if (idx < n) {
            rowoff[idx] = run;
            cursor[idx] = run;
            dinv[idx]   = rsqrtf((float)(vals[i] + 1));
            run += vals[i];
        }
    }
    if (t == 1023) rowoff[n] = run;
}

__global__ void k_fill(const int* __restrict__ src, const int* __restrict__ dst,
                       int* __restrict__ cursor, int* __restrict__ col, int E) {
    int e = blockIdx.x * blockDim.x + threadIdx.x;
    if (e < E) {
        int pos = atomicAdd(&cursor[dst[e]], 1);
        col[pos] = src[e];
    }
}

__global__ void k_split_w_all(const float* __restrict__ W1, const float* __restrict__ W2,
                              const float* __restrict__ W3, unsigned* __restrict__ W1T,
                              unsigned* __restrict__ W2T, unsigned* __restrict__ W3T,
                              int* __restrict__ cnt, int n) {
    int e = blockIdx.x * 256 + threadIdx.x;
    if (e < n) cnt[e] = 0;
    if (e < 128 * 256) {
        int k = e >> 8, nn = e & 255;
        W1T[(size_t)nn * 128 + k] = packsplit_f16(W1[e]);
    } else if (e < 128 * 256 + 256 * 256) {
        int e2 = e - 128 * 256;
        int k = e2 >> 8, nn = e2 & 255;
        W2T[(size_t)nn * 256 + k] = packsplit_f16(W2[e2]);
    } else if (e < 128 * 256 + 256 * 256 + 256 * 64) {
        int e3 = e - 128 * 256 - 256 * 256;
        int k = e3 >> 6, nn = e3 & 63;
        W3T[(size_t)nn * 256 + k] = packsplit_f16(W3[e3]);
    }
}

__global__ void k_prescale(const float* __restrict__ x, const float* __restrict__ dinv,
                           __half* __restrict__ xp, int total4) {
    int i = blockIdx.x * 256 + threadIdx.x;
    if (i >= total4) return;
    float4 v = reinterpret_cast<const float4*>(x)[i];
    float d = dinv[i >> 5];
    reinterpret_cast<uint2*>(xp)[i] =
        make_uint2(f2h_pack(v.x * d, v.y * d), f2h_pack(v.z * d, v.w * d));
}

template<bool HAS_BIAS, bool RELU, bool SCALE>
__global__ __launch_bounds__(256)
void k_gemm_f16(const __half* __restrict__ Ah, const unsigned* __restrict__ WTp,
                const float* __restrict__ bias, const float* __restrict__ dscale,
                __half* __restrict__ Cout, int M, int K, int N) {
    __shared__ __align__(16) char smem[18432];
    const int ntn = N >> 6;
    int tile = blockIdx.y * ntn + blockIdx.x;
    gemm_body<HAS_BIAS, RELU, SCALE>(Ah, WTp, bias, dscale, Cout, M, K, N, smem,
                                     tile, 1 << 30);
}

template<int F, bool HAS_BIAS, bool F16OUT>
__global__ void k_aggregate(const __half* __restrict__ h, const float* __restrict__ bias,
                            const float* __restrict__ dinv, const int* __restrict__ rowoff,
                            const int* __restrict__ col, void* __restrict__ out, int n) {
    int node = blockIdx.x * 4 + (threadIdx.x >> 6);
    agg_body<F, HAS_BIAS, F16OUT>(h, bias, dinv, rowoff, col, out, n, node, 1 << 30);
}

__global__ void k_pool(const float* __restrict__ h, const int* __restrict__ batch,
                       float* __restrict__ out, int n) {
    int g = blockIdx.x;
    int t = threadIdx.x;
    int fgrp = t & 15, rgrp = t >> 4;
    int start = lower_bound(batch, n, g);
    int end   = lower_bound(batch, n, g + 1);
    float4 acc = make_float4(0.f, 0.f, 0.f, 0.f);
    for (int i = start + rgrp; i < end; i += 16) {
        float4 v = *reinterpret_cast<const float4*>(&h[(size_t)i * 64 + fgrp * 4]);
        acc.x += v.x; acc.y += v.y; acc.z += v.z; acc.w += v.w;
    }
    __shared__ float4 red[256];
    red[t] = acc;
    __syncthreads();
#pragma unroll
    for (int off = 8; off >= 1; off >>= 1) {
        if (rgrp < off) {
            float4 o = red[(rgrp + off) * 16 + fgrp];
            float4 m = red[t];
            m.x += o.x; m.y += o.y; m.z += o.z; m.w += o.w;
            red[t] = m;
        }
        __syncthreads();
    }
    if (rgrp == 0) {
        float denom = (float)max(end - start, 1);
        float4 m = red[fgrp];
        *reinterpret_cast<float4*>(&out[g * 64 + fgrp * 4]) =
            make_float4(m.x / denom, m.y / denom, m.z / denom, m.w / denom);
    }
}

// ================= launch =================
extern "C" void kernel_launch(void* const* d_in, const int* in_sizes, int n_in,
                              void* d_out, int out_size, void* d_ws, size_t ws_size,
                              hipStream_t stream) {
    const float* x  = (const float*)d_in[0];
    const int* ei   = (const int*)d_in[1];
    const int* batch = (const int*)d_in[2];
    const float* W1 = (const float*)d_in[3]; const float* b1 = (const float*)d_in[4];
    const float* W2 = (const float*)d_in[5]; const float* b2 = (const float*)d_in[6];
    const float* W3 = (const float*)d_in[7]; const float* b3 = (const float*)d_in[8];

    const int n = in_sizes[0] / 128;
    const int E = in_sizes[1] / 2;

    char* p = (char*)d_ws;
    auto carve = [&](size_t bytes) { char* q = p; p += (bytes + 255) & ~255ULL; return q; };
    char* R1      = carve((size_t)n * 256 * 4);
    char* R2      = carve((size_t)n * 256 * 4);
    float* dinv   = (float*)carve((size_t)n * 4);
    int*   cnt    = (int*)carve((size_t)n * 4);
    int*   rowoff = (int*)carve((size_t)(n + 1) * 4);
    int*   cursor = (int*)carve((size_t)n * 4);
    int*   col    = (int*)carve((size_t)E * 4);
    int*   bsums  = (int*)carve(1024 * 4);
    unsigned* W1T = (unsigned*)carve((size_t)256 * 128 * 4);
    unsigned* W2T = (unsigned*)carve((size_t)256 * 256 * 4);
    unsigned* W3T = (unsigned*)carve((size_t)64 * 256 * 4);

    MegaArgs a;
    a.x = x; a.src = ei; a.dst = ei + E; a.batch = batch;
    a.W1 = W1; a.b1 = b1; a.W2 = W2; a.b2 = b2; a.W3 = W3; a.b3 = b3;
    a.out = (float*)d_out;
    a.n = n; a.E = E;
    a.cnt = cnt; a.rowoff = rowoff; a.cursor = cursor; a.col = col; a.blockSums = bsums;
    a.dinv = dinv;
    a.W1T = W1T; a.W2T = W2T; a.W3T = W3T;
    a.XPh = (__half*)R2;
    a.A0  = (__half*)R1;
    a.H1  = (__half*)R2;
    a.A1  = (__half*)R1;
    a.P2  = (__half*)R2;
    a.T3  = (__half*)R1;
    a.H3  = (float*)R2;

    // Size the cooperative grid from the runtime's own occupancy calc.
    bool coop_ok = false;
    int perCU = 0;
    if (hipOccupancyMaxActiveBlocksPerMultiprocessor(&perCU, k_mega, 256, 0) == hipSuccess
        && perCU > 0) {
        int nb = perCU * 256;            // MI355X: 256 CUs
        if (nb > 1024) nb = 1024;
        // scan needs nb*256 >= n (1 elem/thread); pool needs nb >= 64
        if (nb * 256 >= n && nb >= 80) {
            void* kargs[] = { (void*)&a };
            coop_ok = (hipLaunchCooperativeKernel((void*)k_mega, dim3(nb), dim3(256),
                                                  kargs, 0, stream) == hipSuccess);
        }
    }

    if (!coop_ok) {
        // proven round-10 multi-kernel path
        k_split_w_all<<<(128*256 + 256*256 + 256*64 + 255) / 256, 256, 0, stream>>>(
            W1, W2, W3, W1T, W2T, W3T, cnt, n);
        k_count<<<(E + 255) / 256, 256, 0, stream>>>(a.dst, cnt, E);
        k_scan<<<1, 1024, 0, stream>>>(cnt, rowoff, cursor, dinv, n);
        k_fill<<<(E + 255) / 256, 256, 0, stream>>>(a.src, a.dst, cursor, col, E);

        const int mblocks = (n + 63) / 64;
        k_prescale<<<((n * 32) + 255) / 256, 256, 0, stream>>>(x, dinv, a.XPh, n * 32);
        k_aggregate<128, false, true><<<(n + 3) / 4, 256, 0, stream>>>(
            a.XPh, nullptr, dinv, rowoff, col, a.A0, n);
        k_gemm_f16<true, true, true><<<dim3(4, mblocks), 256, 0, stream>>>(
            a.A0, W1T, b1, dinv, a.H1, n, 128, 256);
        k_aggregate<256, false, true><<<(n + 3) / 4, 256, 0, stream>>>(
            a.H1, nullptr, dinv, rowoff, col, a.A1, n);
        k_gemm_f16<true, true, false><<<dim3(4, mblocks), 256, 0, stream>>>(
            a.A1, W2T, b2, nullptr, a.P2, n, 256, 256);
        k_gemm_f16<false, false, true><<<dim3(1, mblocks), 256, 0, stream>>>(
            a.P2, W3T, nullptr, dinv, a.T3, n, 256, 64);
        k_aggregate<64, true, false><<<(n + 3) / 4, 256, 0, stream>>>(
            a.T3, b3, dinv, rowoff, col, a.H3, n);
        k_pool<<<64, 256, 0, stream>>>(a.H3, batch, (float*)d_out, n);
    }
}

// Round 13
// 271.800 us; speedup vs baseline: 4.5910x; 4.5910x over previous
//
#include <hip/hip_runtime.h>
#include <hip/hip_fp16.h>

typedef __attribute__((ext_vector_type(8))) short short8v;
typedef __attribute__((ext_vector_type(8))) _Float16 half8v;
typedef __attribute__((ext_vector_type(4))) float f32x4;

// NOTE (r12): cooperative grid.sync() measured ~120us/sync on MI355X (1024 blocks,
// cross-XCD atomic spin) -> never use grid-wide sync for phase separation here.

// ---------------- helpers ----------------
__device__ __forceinline__ float h2f_lo(unsigned u) {
    return __half2float(__ushort_as_half((unsigned short)(u & 0xffffu)));
}
__device__ __forceinline__ float h2f_hi(unsigned u) {
    return __half2float(__ushort_as_half((unsigned short)(u >> 16)));
}
__device__ __forceinline__ unsigned f2h_pack(float a, float b) {
    return (unsigned)__half_as_ushort(__float2half(a)) |
           ((unsigned)__half_as_ushort(__float2half(b)) << 16);
}
// split w into f16 hi + f16 lo (w ~= hi+lo, rep err ~2^-24): packed (hi<<16)|lo
__device__ __forceinline__ unsigned packsplit_f16(float v) {
    unsigned short hs = __half_as_ushort(__float2half(v));
    float r = v - __half2float(__ushort_as_half(hs));
    unsigned short ls = __half_as_ushort(__float2half(r));
    return (((unsigned)hs) << 16) | (unsigned)ls;
}
__device__ __forceinline__ void unpack8(const uint4 u0, const uint4 u1,
                                        short8v& hi, short8v& lo) {
    unsigned av[8] = {u0.x, u0.y, u0.z, u0.w, u1.x, u1.y, u1.z, u1.w};
#pragma unroll
    for (int i = 0; i < 8; ++i) {
        hi[i] = (short)(av[i] >> 16);
        lo[i] = (short)(av[i] & 0xffffu);
    }
}
__device__ __forceinline__ int lower_bound(const int* __restrict__ a, int n, int v) {
    int lo = 0, hi = n;
    while (lo < hi) {
        int mid = (lo + hi) >> 1;
        if (a[mid] < v) lo = mid + 1; else hi = mid;
    }
    return lo;
}

// ---------------- CSR build ----------------
__global__ void k_count(const int* __restrict__ dst, int* __restrict__ cnt, int E) {
    int e = blockIdx.x * blockDim.x + threadIdx.x;
    if (e < E) atomicAdd(&cnt[dst[e]], 1);
}

#define SCAN_CHUNK 20
__global__ void k_scan(const int* __restrict__ cnt, int* __restrict__ rowoff,
                       int* __restrict__ cursor, float* __restrict__ dinv, int n) {
    __shared__ int wsum[16];
    int t = threadIdx.x;
    int base = t * SCAN_CHUNK;
    int vals[SCAN_CHUNK];
    int local = 0;
#pragma unroll
    for (int i = 0; i < SCAN_CHUNK; ++i) {
        int idx = base + i;
        vals[i] = (idx < n) ? cnt[idx] : 0;
        local += vals[i];
    }
    int lane = t & 63, wv = t >> 6;
    int incl = local;
#pragma unroll
    for (int off = 1; off < 64; off <<= 1) {
        int u = __shfl_up(incl, off, 64);
        if (lane >= off) incl += u;
    }
    if (lane == 63) wsum[wv] = incl;
    __syncthreads();
    if (t == 0) {
        int run = 0;
#pragma unroll
        for (int i = 0; i < 16; ++i) { int v = wsum[i]; wsum[i] = run; run += v; }
    }
    __syncthreads();
    int run = wsum[wv] + incl - local;
#pragma unroll
    for (int i = 0; i < SCAN_CHUNK; ++i) {
        int idx = base + i;
        if (idx < n) {
            rowoff[idx] = run;
            cursor[idx] = run;
            dinv[idx]   = rsqrtf((float)(vals[i] + 1));
            run += vals[i];
        }
    }
    if (t == 1023) rowoff[n] = run;
}

// fill CSR + prescale x (independent, both depend only on scan)
__global__ void k_fill_prescale(const int* __restrict__ src, const int* __restrict__ dst,
                                int* __restrict__ cursor, int* __restrict__ col, int E,
                                const float* __restrict__ x, const float* __restrict__ dinv,
                                __half* __restrict__ xp, int total4) {
    int i = blockIdx.x * 256 + threadIdx.x;
    if (i < E) {
        int pos = atomicAdd(&cursor[dst[i]], 1);
        col[pos] = src[i];
    }
    if (i < total4) {
        float4 v = reinterpret_cast<const float4*>(x)[i];
        float d = dinv[i >> 5];   // 32 float4 per 128-wide row
        reinterpret_cast<uint2*>(xp)[i] =
            make_uint2(f2h_pack(v.x * d, v.y * d), f2h_pack(v.z * d, v.w * d));
    }
}

// ---------------- W pre-split + cnt zeroing ----------------
__global__ void k_split_w_all(const float* __restrict__ W1, const float* __restrict__ W2,
                              const float* __restrict__ W3, unsigned* __restrict__ W1T,
                              unsigned* __restrict__ W2T, unsigned* __restrict__ W3T,
                              int* __restrict__ cnt, int n) {
    int e = blockIdx.x * 256 + threadIdx.x;
    if (e < n) cnt[e] = 0;
    if (e < 128 * 256) {
        int k = e >> 8, nn = e & 255;
        W1T[(size_t)nn * 128 + k] = packsplit_f16(W1[e]);
    } else if (e < 128 * 256 + 256 * 256) {
        int e2 = e - 128 * 256;
        int k = e2 >> 8, nn = e2 & 255;
        W2T[(size_t)nn * 256 + k] = packsplit_f16(W2[e2]);
    } else if (e < 128 * 256 + 256 * 256 + 256 * 64) {
        int e3 = e - 128 * 256 - 256 * 256;
        int k = e3 >> 6, nn = e3 & 63;
        W3T[(size_t)nn * 256 + k] = packsplit_f16(W3[e3]);
    }
}

// ---------------- Fused aggregate + GEMM (layers 1 & 2) ----------------
// Block b owns rows [bm, bm+64):
//   phase 1: agg those rows (8-deep gather) -> Ash fp16 [64][F+8] in LDS
//   phase 2: GEMM Ash @ W (N=256) with bias+relu (+ optional *dinv), write fp16.
// No A global round-trip; one dispatch instead of two.
template<int F, bool SCALE>
__global__ __launch_bounds__(256)
void k_fused_agg_gemm(const __half* __restrict__ h, const unsigned* __restrict__ WTp,
                      const float* __restrict__ bias, const float* __restrict__ dinv,
                      const int* __restrict__ rowoff, const int* __restrict__ col,
                      __half* __restrict__ Cout, int n) {
    constexpr int N = 256;
    constexpr int VEC = F / 64;              // fp16 per lane per row
    __shared__ __align__(16) _Float16 Ash[64][F + 8];      // +8 fp16 pad -> 2-way banks
    __shared__ __align__(16) unsigned short Bsh[64][72];   // hi 0..31 | lo 32..63
    const int tid = threadIdx.x;
    const int lane = tid & 63, wv = tid >> 6;
    const int bm = blockIdx.x * 64;

    // ---- phase 1: aggregate 64 rows, wave wv handles rows r == wv (mod 4) ----
    for (int r = wv; r < 64; r += 4) {
        int node = bm + r;
        float res[VEC];
#pragma unroll
        for (int v = 0; v < VEC; ++v) res[v] = 0.f;
        if (node < n) {
            float di = dinv[node];
            float acc[8][VEC];
#pragma unroll
            for (int b = 0; b < 8; ++b)
#pragma unroll
                for (int v = 0; v < VEC; ++v) acc[b][v] = 0.f;
            {   // self row
                const __half* ps = &h[(size_t)node * F + lane * VEC];
                if constexpr (VEC == 4) {
                    uint2 u = *reinterpret_cast<const uint2*>(ps);
                    acc[0][0] = h2f_lo(u.x); acc[0][1] = h2f_hi(u.x);
                    acc[0][2] = h2f_lo(u.y); acc[0][3] = h2f_hi(u.y);
                } else {
                    unsigned u = *reinterpret_cast<const unsigned*>(ps);
                    acc[0][0] = h2f_lo(u); acc[0][1] = h2f_hi(u);
                }
            }
            int e = rowoff[node], s1 = rowoff[node + 1];
            for (; e + 7 < s1; e += 8) {
#pragma unroll
                for (int b = 0; b < 8; ++b) {
                    int s = col[e + b];
                    const __half* ps = &h[(size_t)s * F + lane * VEC];
                    if constexpr (VEC == 4) {
                        uint2 u = *reinterpret_cast<const uint2*>(ps);
                        acc[b][0] += h2f_lo(u.x); acc[b][1] += h2f_hi(u.x);
                        acc[b][2] += h2f_lo(u.y); acc[b][3] += h2f_hi(u.y);
                    } else {
                        unsigned u = *reinterpret_cast<const unsigned*>(ps);
                        acc[b][0] += h2f_lo(u); acc[b][1] += h2f_hi(u);
                    }
                }
            }
            for (; e < s1; ++e) {
                int s = col[e];
                const __half* ps = &h[(size_t)s * F + lane * VEC];
                if constexpr (VEC == 4) {
                    uint2 u = *reinterpret_cast<const uint2*>(ps);
                    acc[0][0] += h2f_lo(u.x); acc[0][1] += h2f_hi(u.x);
                    acc[0][2] += h2f_lo(u.y); acc[0][3] += h2f_hi(u.y);
                } else {
                    unsigned u = *reinterpret_cast<const unsigned*>(ps);
                    acc[0][0] += h2f_lo(u); acc[0][1] += h2f_hi(u);
                }
            }
#pragma unroll
            for (int v = 0; v < VEC; ++v)
                res[v] = (((acc[0][v] + acc[1][v]) + (acc[2][v] + acc[3][v])) +
                          ((acc[4][v] + acc[5][v]) + (acc[6][v] + acc[7][v]))) * di;
        }
        if constexpr (VEC == 4)
            *reinterpret_cast<uint2*>(&Ash[r][lane * 4]) =
                make_uint2(f2h_pack(res[0], res[1]), f2h_pack(res[2], res[3]));
        else
            *reinterpret_cast<unsigned*>(&Ash[r][lane * 2]) = f2h_pack(res[0], res[1]);
    }
    __syncthreads();

    // ---- phase 2: GEMM Ash[64][F] @ W[F][256] ----
    const int wm = (wv >> 1) * 32, wn0 = (wv & 1) * 32;
    const int m_st = tid >> 2, kq = tid & 3;

    for (int bn = 0; bn < N; bn += 64) {
        f32x4 acc[2][2];
#pragma unroll
        for (int i = 0; i < 2; ++i)
#pragma unroll
            for (int j = 0; j < 2; ++j) acc[i][j] = (f32x4){0.f, 0.f, 0.f, 0.f};

        for (int k0 = 0; k0 < F; k0 += 32) {
            {   // stage B tile (rows bn+m_st, k-octet kq)
                int nrow = bn + m_st;
                const uint4* g = reinterpret_cast<const uint4*>(&WTp[(size_t)nrow * F + k0 + kq * 8]);
                uint4 u0 = g[0], u1 = g[1];
                short8v hi, lo;
                unpack8(u0, u1, hi, lo);
                *reinterpret_cast<short8v*>(&Bsh[m_st][kq * 8])      = hi;
                *reinterpret_cast<short8v*>(&Bsh[m_st][32 + kq * 8]) = lo;
            }
            __syncthreads();

            half8v a[2], bh[2], bl[2];
#pragma unroll
            for (int mi = 0; mi < 2; ++mi)
                a[mi] = *reinterpret_cast<const half8v*>(
                    &Ash[wm + mi * 16 + (lane & 15)][k0 + (lane >> 4) * 8]);
#pragma unroll
            for (int ni = 0; ni < 2; ++ni) {
                const unsigned short* p = &Bsh[wn0 + ni * 16 + (lane & 15)][(lane >> 4) * 8];
                bh[ni] = *reinterpret_cast<const half8v*>(p);
                bl[ni] = *reinterpret_cast<const half8v*>(p + 32);
            }
#pragma unroll
            for (int mi = 0; mi < 2; ++mi)
#pragma unroll
                for (int ni = 0; ni < 2; ++ni) {
                    acc[mi][ni] = __builtin_amdgcn_mfma_f32_16x16x32_f16(a[mi], bh[ni], acc[mi][ni], 0, 0, 0);
                    acc[mi][ni] = __builtin_amdgcn_mfma_f32_16x16x32_f16(a[mi], bl[ni], acc[mi][ni], 0, 0, 0);
                }
            __syncthreads();
        }

        // epilogue: D row=(lane>>4)*4+j, col=lane&15 (verified C/D mapping); bias+relu
#pragma unroll
        for (int mi = 0; mi < 2; ++mi)
#pragma unroll
            for (int ni = 0; ni < 2; ++ni) {
                int colg = bn + wn0 + ni * 16 + (lane & 15);
                int rowb = bm + wm + mi * 16 + ((lane >> 4) << 2);
                float bv = bias[colg];
#pragma unroll
                for (int j = 0; j < 4; ++j) {
                    int row = rowb + j;
                    if (row < n) {
                        float v = fmaxf(acc[mi][ni][j] + bv, 0.f);
                        if constexpr (SCALE) v *= dinv[row];
                        Cout[(size_t)row * N + colg] = __float2half(v);
                    }
                }
            }
    }
}

// ---------------- standalone GEMM (layer 3): no bias/relu, *dinv[row] ----------------
__global__ __launch_bounds__(256)
void k_gemm3(const __half* __restrict__ Ah, const unsigned* __restrict__ WTp,
             const float* __restrict__ dscale, __half* __restrict__ Cout,
             int M, int K, int N) {
    __shared__ __align__(16) _Float16      Ash[64][72];
    __shared__ __align__(16) unsigned short Bsh[64][72];
    const int tid = threadIdx.x;
    const int bm = blockIdx.y * 64, bn = blockIdx.x * 64;
    const int lane = tid & 63, w = tid >> 6;
    const int wm = (w >> 1) * 32, wn = (w & 1) * 32;
    const int m_st = tid >> 2, kq = tid & 3;

    f32x4 acc[2][2];
#pragma unroll
    for (int i = 0; i < 2; ++i)
#pragma unroll
        for (int j = 0; j < 2; ++j) acc[i][j] = (f32x4){0.f, 0.f, 0.f, 0.f};

    for (int k0 = 0; k0 < K; k0 += 32) {
        {
            int row = bm + m_st;
            uint4 u = {0, 0, 0, 0};
            if (row < M)
                u = *reinterpret_cast<const uint4*>(&Ah[(size_t)row * K + k0 + kq * 8]);
            *reinterpret_cast<uint4*>(&Ash[m_st][kq * 8]) = u;
        }
        {
            int nrow = bn + m_st;
            const uint4* g = reinterpret_cast<const uint4*>(&WTp[(size_t)nrow * K + k0 + kq * 8]);
            uint4 u0 = g[0], u1 = g[1];
            short8v hi, lo;
            unpack8(u0, u1, hi, lo);
            *reinterpret_cast<short8v*>(&Bsh[m_st][kq * 8])      = hi;
            *reinterpret_cast<short8v*>(&Bsh[m_st][32 + kq * 8]) = lo;
        }
        __syncthreads();

        half8v a[2], bh[2], bl[2];
#pragma unroll
        for (int mi = 0; mi < 2; ++mi)
            a[mi] = *reinterpret_cast<const half8v*>(&Ash[wm + mi * 16 + (lane & 15)][(lane >> 4) * 8]);
#pragma unroll
        for (int ni = 0; ni < 2; ++ni) {
            const unsigned short* p = &Bsh[wn + ni * 16 + (lane & 15)][(lane >> 4) * 8];
            bh[ni] = *reinterpret_cast<const half8v*>(p);
            bl[ni] = *reinterpret_cast<const half8v*>(p + 32);
        }
#pragma unroll
        for (int mi = 0; mi < 2; ++mi)
#pragma unroll
            for (int ni = 0; ni < 2; ++ni) {
                acc[mi][ni] = __builtin_amdgcn_mfma_f32_16x16x32_f16(a[mi], bh[ni], acc[mi][ni], 0, 0, 0);
                acc[mi][ni] = __builtin_amdgcn_mfma_f32_16x16x32_f16(a[mi], bl[ni], acc[mi][ni], 0, 0, 0);
            }
        __syncthreads();
    }

#pragma unroll
    for (int mi = 0; mi < 2; ++mi)
#pragma unroll
        for (int ni = 0; ni < 2; ++ni) {
            int colg = bn + wn + ni * 16 + (lane & 15);
            int rowb = bm + wm + mi * 16 + ((lane >> 4) << 2);
#pragma unroll
            for (int j = 0; j < 4; ++j) {
                int row = rowb + j;
                if (row < M) {
                    float v = acc[mi][ni][j] * dscale[row];
                    Cout[(size_t)row * N + colg] = __float2half(v);
                }
            }
        }
}

// ---------------- Aggregate F=64 (layer 3 tail): +bias, f32 out ----------------
__global__ void k_agg64(const __half* __restrict__ h, const float* __restrict__ bias,
                        const float* __restrict__ dinv, const int* __restrict__ rowoff,
                        const int* __restrict__ col, float* __restrict__ out, int n) {
    int lane = threadIdx.x & 63;
    int wid  = threadIdx.x >> 6;
    int node = blockIdx.x * 4 + wid;
    if (node >= n) return;
    float di = dinv[node];
    float acc[4] = {0.f, 0.f, 0.f, 0.f};
    acc[0] = __half2float(h[(size_t)node * 64 + lane]);
    int e = rowoff[node], s1 = rowoff[node + 1];
    for (; e + 3 < s1; e += 4) {
        int s_0 = col[e], s_1 = col[e + 1], s_2 = col[e + 2], s_3 = col[e + 3];
        acc[0] += __half2float(h[(size_t)s_0 * 64 + lane]);
        acc[1] += __half2float(h[(size_t)s_1 * 64 + lane]);
        acc[2] += __half2float(h[(size_t)s_2 * 64 + lane]);
        acc[3] += __half2float(h[(size_t)s_3 * 64 + lane]);
    }
    for (; e < s1; ++e)
        acc[0] += __half2float(h[(size_t)col[e] * 64 + lane]);
    float r = ((acc[0] + acc[1]) + (acc[2] + acc[3])) * di + bias[lane];
    out[(size_t)node * 64 + lane] = r;
}

// ---------------- Global mean pool ----------------
__global__ void k_pool(const float* __restrict__ h, const int* __restrict__ batch,
                       float* __restrict__ out, int n) {
    int g = blockIdx.x;
    int t = threadIdx.x;
    int fgrp = t & 15, rgrp = t >> 4;
    int start = lower_bound(batch, n, g);
    int end   = lower_bound(batch, n, g + 1);
    float4 acc = make_float4(0.f, 0.f, 0.f, 0.f);
    for (int i = start + rgrp; i < end; i += 16) {
        float4 v = *reinterpret_cast<const float4*>(&h[(size_t)i * 64 + fgrp * 4]);
        acc.x += v.x; acc.y += v.y; acc.z += v.z; acc.w += v.w;
    }
    __shared__ float4 red[256];
    red[t] = acc;
    __syncthreads();
#pragma unroll
    for (int off = 8; off >= 1; off >>= 1) {
        if (rgrp < off) {
            float4 o = red[(rgrp + off) * 16 + fgrp];
            float4 m = red[t];
            m.x += o.x; m.y += o.y; m.z += o.z; m.w += o.w;
            red[t] = m;
        }
        __syncthreads();
    }
    if (rgrp == 0) {
        float denom = (float)max(end - start, 1);
        float4 m = red[fgrp];
        *reinterpret_cast<float4*>(&out[g * 64 + fgrp * 4]) =
            make_float4(m.x / denom, m.y / denom, m.z / denom, m.w / denom);
    }
}

// ---------------- Launch ----------------
extern "C" void kernel_launch(void* const* d_in, const int* in_sizes, int n_in,
                              void* d_out, int out_size, void* d_ws, size_t ws_size,
                              hipStream_t stream) {
    const float* x  = (const float*)d_in[0];
    const int* ei   = (const int*)d_in[1];
    const int* batch = (const int*)d_in[2];
    const float* W1 = (const float*)d_in[3]; const float* b1 = (const float*)d_in[4];
    const float* W2 = (const float*)d_in[5]; const float* b2 = (const float*)d_in[6];
    const float* W3 = (const float*)d_in[7]; const float* b3 = (const float*)d_in[8];
    float* out = (float*)d_out;

    const int n = in_sizes[0] / 128;
    const int E = in_sizes[1] / 2;
    const int* src = ei;
    const int* dst = ei + E;

    char* p = (char*)d_ws;
    auto carve = [&](size_t bytes) { char* q = p; p += (bytes + 255) & ~255ULL; return q; };
    char* R1      = carve((size_t)n * 256 * 4);
    char* R2      = carve((size_t)n * 256 * 4);
    float* dinv   = (float*)carve((size_t)n * 4);
    int*   cnt    = (int*)carve((size_t)n * 4);
    int*   rowoff = (int*)carve((size_t)(n + 1) * 4);
    int*   cursor = (int*)carve((size_t)n * 4);
    int*   col    = (int*)carve((size_t)E * 4);
    unsigned* W1T = (unsigned*)carve((size_t)256 * 128 * 4);
    unsigned* W2T = (unsigned*)carve((size_t)256 * 256 * 4);
    unsigned* W3T = (unsigned*)carve((size_t)64 * 256 * 4);

    // region aliases (lifetimes disjoint):
    __half* XPh = (__half*)R2;       // fp16(dinv.*x) [n][128]; gather src of fused-1
    __half* H1  = (__half*)R1;       // fused-1 out (scaled) fp16 [n][256]
    __half* P2  = (__half*)R2;       // fused-2 out fp16 [n][256] (XPh dead)
    __half* T3  = (__half*)R1;       // gemm3 out (scaled) fp16 [n][64] (H1 dead)
    float*  H3  = (float*)R2;        // agg64 out f32 [n][64] (P2 dead)

    // 1: W split + cnt zero
    k_split_w_all<<<(128*256 + 256*256 + 256*64 + 255) / 256, 256, 0, stream>>>(
        W1, W2, W3, W1T, W2T, W3T, cnt, n);
    // 2: degree count
    k_count<<<(E + 255) / 256, 256, 0, stream>>>(dst, cnt, E);
    // 3: scan -> rowoff/cursor/dinv
    k_scan<<<1, 1024, 0, stream>>>(cnt, rowoff, cursor, dinv, n);
    // 4: CSR fill + x prescale (fused)
    {
        int total4 = n * 32;
        int mx = total4 > E ? total4 : E;
        k_fill_prescale<<<(mx + 255) / 256, 256, 0, stream>>>(
            src, dst, cursor, col, E, x, dinv, XPh, total4);
    }
    const int mblocks = (n + 63) / 64;
    // 5: layer 1 fused: agg(XPh) -> LDS -> @W1 + b1, relu, *dinv -> H1
    k_fused_agg_gemm<128, true><<<mblocks, 256, 0, stream>>>(
        XPh, W1T, b1, dinv, rowoff, col, H1, n);
    // 6: layer 2 fused: agg(H1) -> LDS -> @W2 + b2, relu -> P2
    k_fused_agg_gemm<256, false><<<mblocks, 256, 0, stream>>>(
        H1, W2T, b2, dinv, rowoff, col, P2, n);
    // 7: layer 3 GEMM: T3 = (P2 @ W3) .* dinv
    k_gemm3<<<dim3(1, mblocks), 256, 0, stream>>>(P2, W3T, dinv, T3, n, 256, 64);
    // 8: layer 3 aggregate: H3 = dinv.*(gather-sum T3) + b3
    k_agg64<<<(n + 3) / 4, 256, 0, stream>>>(T3, b3, dinv, rowoff, col, H3, n);
    // 9: pool
    k_pool<<<64, 256, 0, stream>>>(H3, batch, out, n);
}

// Round 14
// 188.576 us; speedup vs baseline: 6.6171x; 1.4413x over previous
//
#include <hip/hip_runtime.h>
#include <hip/hip_fp16.h>

typedef __attribute__((ext_vector_type(8))) short short8v;
typedef __attribute__((ext_vector_type(8))) _Float16 half8v;
typedef __attribute__((ext_vector_type(4))) float f32x4;

// r12 lesson: grid.sync() ~120us on MI355X -> never grid-sync for phases.
// r13 lesson: agg+GEMM fusion caps grid at tile count -> starves gather occupancy.

// ---------------- helpers ----------------
__device__ __forceinline__ float h2f_lo(unsigned u) {
    return __half2float(__ushort_as_half((unsigned short)(u & 0xffffu)));
}
__device__ __forceinline__ float h2f_hi(unsigned u) {
    return __half2float(__ushort_as_half((unsigned short)(u >> 16)));
}
__device__ __forceinline__ unsigned f2h_pack(float a, float b) {
    return (unsigned)__half_as_ushort(__float2half(a)) |
           ((unsigned)__half_as_ushort(__float2half(b)) << 16);
}
__device__ __forceinline__ unsigned packsplit_f16(float v) {
    unsigned short hs = __half_as_ushort(__float2half(v));
    float r = v - __half2float(__ushort_as_half(hs));
    unsigned short ls = __half_as_ushort(__float2half(r));
    return (((unsigned)hs) << 16) | (unsigned)ls;
}
__device__ __forceinline__ void unpack8(const uint4 u0, const uint4 u1,
                                        short8v& hi, short8v& lo) {
    unsigned av[8] = {u0.x, u0.y, u0.z, u0.w, u1.x, u1.y, u1.z, u1.w};
#pragma unroll
    for (int i = 0; i < 8; ++i) {
        hi[i] = (short)(av[i] >> 16);
        lo[i] = (short)(av[i] & 0xffffu);
    }
}
__device__ __forceinline__ int lower_bound(const int* __restrict__ a, int n, int v) {
    int lo = 0, hi = n;
    while (lo < hi) {
        int mid = (lo + hi) >> 1;
        if (a[mid] < v) lo = mid + 1; else hi = mid;
    }
    return lo;
}

// ---------------- CSR build ----------------
__global__ void k_count(const int* __restrict__ dst, int* __restrict__ cnt, int E) {
    int e = blockIdx.x * blockDim.x + threadIdx.x;
    if (e < E) atomicAdd(&cnt[dst[e]], 1);
}

// 1 block x 1024: scan + dinv; threads 0..63 also compute gcinv[g]=1/max(nodes_g,1).
#define SCAN_CHUNK 20
__global__ void k_scan(const int* __restrict__ cnt, int* __restrict__ rowoff,
                       int* __restrict__ cursor, float* __restrict__ dinv, int n,
                       const int* __restrict__ batch, float* __restrict__ gcinv) {
    __shared__ int wsum[16];
    int t = threadIdx.x;
    int base = t * SCAN_CHUNK;
    int vals[SCAN_CHUNK];
    int local = 0;
#pragma unroll
    for (int i = 0; i < SCAN_CHUNK; ++i) {
        int idx = base + i;
        vals[i] = (idx < n) ? cnt[idx] : 0;
        local += vals[i];
    }
    int lane = t & 63, wv = t >> 6;
    int incl = local;
#pragma unroll
    for (int off = 1; off < 64; off <<= 1) {
        int u = __shfl_up(incl, off, 64);
        if (lane >= off) incl += u;
    }
    if (lane == 63) wsum[wv] = incl;
    __syncthreads();
    if (t == 0) {
        int run = 0;
#pragma unroll
        for (int i = 0; i < 16; ++i) { int v = wsum[i]; wsum[i] = run; run += v; }
    }
    __syncthreads();
    int run = wsum[wv] + incl - local;
#pragma unroll
    for (int i = 0; i < SCAN_CHUNK; ++i) {
        int idx = base + i;
        if (idx < n) {
            rowoff[idx] = run;
            cursor[idx] = run;
            dinv[idx]   = rsqrtf((float)(vals[i] + 1));
            run += vals[i];
        }
    }
    if (t == 1023) rowoff[n] = run;
    // per-graph inverse counts (batch sorted): 64 binary searches
    if (t < 64) {
        int s = lower_bound(batch, n, t);
        int e = lower_bound(batch, n, t + 1);
        gcinv[t] = 1.0f / (float)max(e - s, 1);
    }
}

// CSR fill + x prescale (independent, both depend only on scan)
__global__ void k_fill_prescale(const int* __restrict__ src, const int* __restrict__ dst,
                                int* __restrict__ cursor, int* __restrict__ col, int E,
                                const float* __restrict__ x, const float* __restrict__ dinv,
                                __half* __restrict__ xp, int total4) {
    int i = blockIdx.x * 256 + threadIdx.x;
    if (i < E) {
        int pos = atomicAdd(&cursor[dst[i]], 1);
        col[pos] = src[i];
    }
    if (i < total4) {
        float4 v = reinterpret_cast<const float4*>(x)[i];
        float d = dinv[i >> 5];   // 32 float4 per 128-wide row
        reinterpret_cast<uint2*>(xp)[i] =
            make_uint2(f2h_pack(v.x * d, v.y * d), f2h_pack(v.z * d, v.w * d));
    }
}

// ---------------- W pre-split + cnt zeroing + d_out zeroing ----------------
__global__ void k_split_w_all(const float* __restrict__ W1, const float* __restrict__ W2,
                              const float* __restrict__ W3, unsigned* __restrict__ W1T,
                              unsigned* __restrict__ W2T, unsigned* __restrict__ W3T,
                              int* __restrict__ cnt, int n,
                              float* __restrict__ out, int outsz) {
    int e = blockIdx.x * 256 + threadIdx.x;
    if (e < n) cnt[e] = 0;
    if (e < outsz) out[e] = 0.f;   // pool accumulates via atomics; re-zero every call
    if (e < 128 * 256) {
        int k = e >> 8, nn = e & 255;
        W1T[(size_t)nn * 128 + k] = packsplit_f16(W1[e]);
    } else if (e < 128 * 256 + 256 * 256) {
        int e2 = e - 128 * 256;
        int k = e2 >> 8, nn = e2 & 255;
        W2T[(size_t)nn * 256 + k] = packsplit_f16(W2[e2]);
    } else if (e < 128 * 256 + 256 * 256 + 256 * 64) {
        int e3 = e - 128 * 256 - 256 * 256;
        int k = e3 >> 6, nn = e3 & 63;
        W3T[(size_t)nn * 256 + k] = packsplit_f16(W3[e3]);
    }
}

// ---------------- MFMA f16 GEMM (round-10 proven) ----------------
template<bool HAS_BIAS, bool RELU, bool SCALE>
__global__ __launch_bounds__(256)
void k_gemm_f16(const __half* __restrict__ Ah, const unsigned* __restrict__ WTp,
                const float* __restrict__ bias, const float* __restrict__ dscale,
                __half* __restrict__ Cout, int M, int K, int N) {
    __shared__ __align__(16) _Float16      Ash[64][72];
    __shared__ __align__(16) unsigned short Bsh[64][72];
    const int tid = threadIdx.x;
    const int bm = blockIdx.y * 64, bn = blockIdx.x * 64;
    const int lane = tid & 63, w = tid >> 6;
    const int wm = (w >> 1) * 32, wn = (w & 1) * 32;
    const int m_st = tid >> 2, kq = tid & 3;

    f32x4 acc[2][2];
#pragma unroll
    for (int i = 0; i < 2; ++i)
#pragma unroll
        for (int j = 0; j < 2; ++j) acc[i][j] = (f32x4){0.f, 0.f, 0.f, 0.f};

    for (int k0 = 0; k0 < K; k0 += 32) {
        {
            int row = bm + m_st;
            uint4 u = {0, 0, 0, 0};
            if (row < M)
                u = *reinterpret_cast<const uint4*>(&Ah[(size_t)row * K + k0 + kq * 8]);
            *reinterpret_cast<uint4*>(&Ash[m_st][kq * 8]) = u;
        }
        {
            int nrow = bn + m_st;
            const uint4* g = reinterpret_cast<const uint4*>(&WTp[(size_t)nrow * K + k0 + kq * 8]);
            uint4 u0 = g[0], u1 = g[1];
            short8v hi, lo;
            unpack8(u0, u1, hi, lo);
            *reinterpret_cast<short8v*>(&Bsh[m_st][kq * 8])      = hi;
            *reinterpret_cast<short8v*>(&Bsh[m_st][32 + kq * 8]) = lo;
        }
        __syncthreads();

        half8v a[2], bh[2], bl[2];
#pragma unroll
        for (int mi = 0; mi < 2; ++mi)
            a[mi] = *reinterpret_cast<const half8v*>(&Ash[wm + mi * 16 + (lane & 15)][(lane >> 4) * 8]);
#pragma unroll
        for (int ni = 0; ni < 2; ++ni) {
            const unsigned short* p = &Bsh[wn + ni * 16 + (lane & 15)][(lane >> 4) * 8];
            bh[ni] = *reinterpret_cast<const half8v*>(p);
            bl[ni] = *reinterpret_cast<const half8v*>(p + 32);
        }
#pragma unroll
        for (int mi = 0; mi < 2; ++mi)
#pragma unroll
            for (int ni = 0; ni < 2; ++ni) {
                acc[mi][ni] = __builtin_amdgcn_mfma_f32_16x16x32_f16(a[mi], bh[ni], acc[mi][ni], 0, 0, 0);
                acc[mi][ni] = __builtin_amdgcn_mfma_f32_16x16x32_f16(a[mi], bl[ni], acc[mi][ni], 0, 0, 0);
            }
        __syncthreads();
    }

    // epilogue: D row=(lane>>4)*4+j, col=lane&15 (verified C/D mapping)
#pragma unroll
    for (int mi = 0; mi < 2; ++mi)
#pragma unroll
        for (int ni = 0; ni < 2; ++ni) {
            int colg = bn + wn + ni * 16 + (lane & 15);
            int rowb = bm + wm + mi * 16 + ((lane >> 4) << 2);
            float bv = 0.f;
            if constexpr (HAS_BIAS) bv = bias[colg];
#pragma unroll
            for (int j = 0; j < 4; ++j) {
                int row = rowb + j;
                if (row < M) {
                    float v = acc[mi][ni][j] + bv;
                    if constexpr (RELU) v = fmaxf(v, 0.f);
                    if constexpr (SCALE) v *= dscale[row];
                    Cout[(size_t)row * N + colg] = __float2half(v);
                }
            }
        }
}

// ---------------- Aggregate (round-10 proven): fp16 in, 4 banks, fp16 out ----------------
template<int F>
__global__ void k_aggregate(const __half* __restrict__ h,
                            const float* __restrict__ dinv, const int* __restrict__ rowoff,
                            const int* __restrict__ col, unsigned* __restrict__ out, int n) {
    constexpr int VEC = F / 64;
    int lane = threadIdx.x & 63;
    int wid  = threadIdx.x >> 6;
    int node = blockIdx.x * 4 + wid;
    if (node >= n) return;
    float di = dinv[node];
    float acc[4][VEC];
#pragma unroll
    for (int b = 0; b < 4; ++b)
#pragma unroll
        for (int v = 0; v < VEC; ++v) acc[b][v] = 0.f;
    {
        const __half* ps = &h[(size_t)node * F + lane * VEC];
        if constexpr (VEC == 4) {
            uint2 u = *reinterpret_cast<const uint2*>(ps);
            acc[0][0] = h2f_lo(u.x); acc[0][1] = h2f_hi(u.x);
            acc[0][2] = h2f_lo(u.y); acc[0][3] = h2f_hi(u.y);
        } else {
            unsigned u = *reinterpret_cast<const unsigned*>(ps);
            acc[0][0] = h2f_lo(u); acc[0][1] = h2f_hi(u);
        }
    }
    int e = rowoff[node], s1 = rowoff[node + 1];
    for (; e + 3 < s1; e += 4) {
        int s_0 = col[e], s_1 = col[e + 1], s_2 = col[e + 2], s_3 = col[e + 3];
        const __half* p0 = &h[(size_t)s_0 * F + lane * VEC];
        const __half* p1 = &h[(size_t)s_1 * F + lane * VEC];
        const __half* p2 = &h[(size_t)s_2 * F + lane * VEC];
        const __half* p3 = &h[(size_t)s_3 * F + lane * VEC];
        if constexpr (VEC == 4) {
            uint2 u0 = *reinterpret_cast<const uint2*>(p0);
            uint2 u1 = *reinterpret_cast<const uint2*>(p1);
            uint2 u2 = *reinterpret_cast<const uint2*>(p2);
            uint2 u3 = *reinterpret_cast<const uint2*>(p3);
            acc[0][0] += h2f_lo(u0.x); acc[0][1] += h2f_hi(u0.x);
            acc[0][2] += h2f_lo(u0.y); acc[0][3] += h2f_hi(u0.y);
            acc[1][0] += h2f_lo(u1.x); acc[1][1] += h2f_hi(u1.x);
            acc[1][2] += h2f_lo(u1.y); acc[1][3] += h2f_hi(u1.y);
            acc[2][0] += h2f_lo(u2.x); acc[2][1] += h2f_hi(u2.x);
            acc[2][2] += h2f_lo(u2.y); acc[2][3] += h2f_hi(u2.y);
            acc[3][0] += h2f_lo(u3.x); acc[3][1] += h2f_hi(u3.x);
            acc[3][2] += h2f_lo(u3.y); acc[3][3] += h2f_hi(u3.y);
        } else {
            unsigned u0 = *reinterpret_cast<const unsigned*>(p0);
            unsigned u1 = *reinterpret_cast<const unsigned*>(p1);
            unsigned u2 = *reinterpret_cast<const unsigned*>(p2);
            unsigned u3 = *reinterpret_cast<const unsigned*>(p3);
            acc[0][0] += h2f_lo(u0); acc[0][1] += h2f_hi(u0);
            acc[1][0] += h2f_lo(u1); acc[1][1] += h2f_hi(u1);
            acc[2][0] += h2f_lo(u2); acc[2][1] += h2f_hi(u2);
            acc[3][0] += h2f_lo(u3); acc[3][1] += h2f_hi(u3);
        }
    }
    for (; e < s1; ++e) {
        int s = col[e];
        const __half* ps = &h[(size_t)s * F + lane * VEC];
        if constexpr (VEC == 4) {
            uint2 u = *reinterpret_cast<const uint2*>(ps);
            acc[0][0] += h2f_lo(u.x); acc[0][1] += h2f_hi(u.x);
            acc[0][2] += h2f_lo(u.y); acc[0][3] += h2f_hi(u.y);
        } else {
            unsigned u = *reinterpret_cast<const unsigned*>(ps);
            acc[0][0] += h2f_lo(u); acc[0][1] += h2f_hi(u);
        }
    }

    float r[VEC];
#pragma unroll
    for (int v = 0; v < VEC; ++v)
        r[v] = ((acc[0][v] + acc[1][v]) + (acc[2][v] + acc[3][v])) * di;

    if constexpr (VEC == 4)
        *reinterpret_cast<uint2*>(&out[(size_t)node * 2 * 64 + lane * 2]) =
            make_uint2(f2h_pack(r[0], r[1]), f2h_pack(r[2], r[3]));
    else
        out[(size_t)node * 64 + lane] = f2h_pack(r[0], r[1]);
}

// ---------------- Layer-3 aggregate + mean-pool via per-graph atomics ----------------
// r = dinv*(gather-sum T3) + b3; atomicAdd(out[batch[node]*64+lane], r*gcinv[g]).
__global__ void k_agg64_pool(const __half* __restrict__ h, const float* __restrict__ bias,
                             const float* __restrict__ dinv, const int* __restrict__ rowoff,
                             const int* __restrict__ col, const int* __restrict__ batch,
                             const float* __restrict__ gcinv, float* __restrict__ out, int n) {
    int lane = threadIdx.x & 63;
    int wid  = threadIdx.x >> 6;
    int node = blockIdx.x * 4 + wid;
    if (node >= n) return;
    float di = dinv[node];
    float acc[4] = {0.f, 0.f, 0.f, 0.f};
    acc[0] = __half2float(h[(size_t)node * 64 + lane]);
    int e = rowoff[node], s1 = rowoff[node + 1];
    for (; e + 3 < s1; e += 4) {
        int s_0 = col[e], s_1 = col[e + 1], s_2 = col[e + 2], s_3 = col[e + 3];
        acc[0] += __half2float(h[(size_t)s_0 * 64 + lane]);
        acc[1] += __half2float(h[(size_t)s_1 * 64 + lane]);
        acc[2] += __half2float(h[(size_t)s_2 * 64 + lane]);
        acc[3] += __half2float(h[(size_t)s_3 * 64 + lane]);
    }
    for (; e < s1; ++e)
        acc[0] += __half2float(h[(size_t)col[e] * 64 + lane]);
    float r = ((acc[0] + acc[1]) + (acc[2] + acc[3])) * di + bias[lane];
    int g = batch[node];
    atomicAdd(&out[g * 64 + lane], r * gcinv[g]);
}

// ---------------- Launch ----------------
extern "C" void kernel_launch(void* const* d_in, const int* in_sizes, int n_in,
                              void* d_out, int out_size, void* d_ws, size_t ws_size,
                              hipStream_t stream) {
    const float* x  = (const float*)d_in[0];
    const int* ei   = (const int*)d_in[1];
    const int* batch = (const int*)d_in[2];
    const float* W1 = (const float*)d_in[3]; const float* b1 = (const float*)d_in[4];
    const float* W2 = (const float*)d_in[5]; const float* b2 = (const float*)d_in[6];
    const float* W3 = (const float*)d_in[7]; const float* b3 = (const float*)d_in[8];
    float* out = (float*)d_out;

    const int n = in_sizes[0] / 128;
    const int E = in_sizes[1] / 2;
    const int* src = ei;
    const int* dst = ei + E;

    char* p = (char*)d_ws;
    auto carve = [&](size_t bytes) { char* q = p; p += (bytes + 255) & ~255ULL; return q; };
    char* R1      = carve((size_t)n * 256 * 4);
    char* R2      = carve((size_t)n * 256 * 4);
    float* dinv   = (float*)carve((size_t)n * 4);
    int*   cnt    = (int*)carve((size_t)n * 4);
    int*   rowoff = (int*)carve((size_t)(n + 1) * 4);
    int*   cursor = (int*)carve((size_t)n * 4);
    int*   col    = (int*)carve((size_t)E * 4);
    float* gcinv  = (float*)carve(64 * 4);
    unsigned* W1T = (unsigned*)carve((size_t)256 * 128 * 4);
    unsigned* W2T = (unsigned*)carve((size_t)256 * 256 * 4);
    unsigned* W3T = (unsigned*)carve((size_t)64 * 256 * 4);

    // region aliases (lifetimes disjoint):
    __half*   XPh = (__half*)R2;     // fp16(dinv.*x) [n][128]
    unsigned* A0  = (unsigned*)R1;   // agg0 out fp16-pairs [n][128]
    __half*   H1  = (__half*)R2;     // gemm1 out (scaled) fp16 [n][256] (XPh dead)
    unsigned* A1  = (unsigned*)R1;   // agg1 out fp16-pairs [n][256] (A0 dead)
    __half*   P2  = (__half*)R2;     // gemm2 out fp16 [n][256] (H1 dead)
    __half*   T3  = (__half*)R1;     // gemm3 out (scaled) fp16 [n][64] (A1 dead)

    // 1: W split + cnt zero + d_out zero (pool accumulates atomically)
    k_split_w_all<<<(128*256 + 256*256 + 256*64 + 255) / 256, 256, 0, stream>>>(
        W1, W2, W3, W1T, W2T, W3T, cnt, n, out, out_size);
    // 2: degree count
    k_count<<<(E + 255) / 256, 256, 0, stream>>>(dst, cnt, E);
    // 3: scan -> rowoff/cursor/dinv + gcinv
    k_scan<<<1, 1024, 0, stream>>>(cnt, rowoff, cursor, dinv, n, batch, gcinv);
    // 4: CSR fill + x prescale (fused)
    {
        int total4 = n * 32;
        int mx = total4 > E ? total4 : E;
        k_fill_prescale<<<(mx + 255) / 256, 256, 0, stream>>>(
            src, dst, cursor, col, E, x, dinv, XPh, total4);
    }
    const int mblocks = (n + 63) / 64;
    // 5: agg0 = fp16(dinv.*(gather-sum XPh))
    k_aggregate<128><<<(n + 3) / 4, 256, 0, stream>>>(
        XPh, dinv, rowoff, col, A0, n);
    // 6: H1 = fp16( relu(A0@W1+b1) .* dinv )
    k_gemm_f16<true, true, true><<<dim3(4, mblocks), 256, 0, stream>>>(
        (const __half*)A0, W1T, b1, dinv, H1, n, 128, 256);
    // 7: agg1 = fp16(dinv.*(gather-sum H1))
    k_aggregate<256><<<(n + 3) / 4, 256, 0, stream>>>(
        H1, dinv, rowoff, col, A1, n);
    // 8: P2 = fp16(relu(A1@W2+b2))
    k_gemm_f16<true, true, false><<<dim3(4, mblocks), 256, 0, stream>>>(
        (const __half*)A1, W2T, b2, nullptr, P2, n, 256, 256);
    // 9: T3 = fp16( (P2@W3) .* dinv )
    k_gemm_f16<false, false, true><<<dim3(1, mblocks), 256, 0, stream>>>(
        P2, W3T, nullptr, dinv, T3, n, 256, 64);
    // 10: layer-3 aggregate + mean pool (atomic)
    k_agg64_pool<<<(n + 3) / 4, 256, 0, stream>>>(
        T3, b3, dinv, rowoff, col, batch, gcinv, out, n);
}

// Round 15
// 186.323 us; speedup vs baseline: 6.6971x; 1.0121x over previous
//
#include <hip/hip_runtime.h>
#include <hip/hip_fp16.h>

typedef __attribute__((ext_vector_type(8))) _Float16 half8v;
typedef __attribute__((ext_vector_type(4))) float f32x4;

// r12: grid.sync() ~120us on MI355X -> never grid-sync for phases.
// r13: agg+GEMM fusion caps grid at tile count -> starves gather occupancy.
// r14: dispatch boundaries ~0-1us -> don't chase dispatch count.
//      aggs at compulsory cross-XCD replication floor (8 XCD x footprint @ ~3.6TB/s).

// ---------------- helpers ----------------
__device__ __forceinline__ float h2f_lo(unsigned u) {
    return __half2float(__ushort_as_half((unsigned short)(u & 0xffffu)));
}
__device__ __forceinline__ float h2f_hi(unsigned u) {
    return __half2float(__ushort_as_half((unsigned short)(u >> 16)));
}
__device__ __forceinline__ unsigned f2h_pack(float a, float b) {
    return (unsigned)__half_as_ushort(__float2half(a)) |
           ((unsigned)__half_as_ushort(__float2half(b)) << 16);
}
__device__ __forceinline__ int lower_bound(const int* __restrict__ a, int n, int v) {
    int lo = 0, hi = n;
    while (lo < hi) {
        int mid = (lo + hi) >> 1;
        if (a[mid] < v) lo = mid + 1; else hi = mid;
    }
    return lo;
}

// ---------------- CSR build ----------------
__global__ void k_count(const int* __restrict__ dst, int* __restrict__ cnt, int E) {
    int e = blockIdx.x * blockDim.x + threadIdx.x;
    if (e < E) atomicAdd(&cnt[dst[e]], 1);
}

// 1 block x 1024: scan + dinv; threads 0..63 also compute gcinv[g].
#define SCAN_CHUNK 20
__global__ void k_scan(const int* __restrict__ cnt, int* __restrict__ rowoff,
                       int* __restrict__ cursor, float* __restrict__ dinv, int n,
                       const int* __restrict__ batch, float* __restrict__ gcinv) {
    __shared__ int wsum[16];
    int t = threadIdx.x;
    int base = t * SCAN_CHUNK;
    int vals[SCAN_CHUNK];
    int local = 0;
#pragma unroll
    for (int i = 0; i < SCAN_CHUNK; ++i) {
        int idx = base + i;
        vals[i] = (idx < n) ? cnt[idx] : 0;
        local += vals[i];
    }
    int lane = t & 63, wv = t >> 6;
    int incl = local;
#pragma unroll
    for (int off = 1; off < 64; off <<= 1) {
        int u = __shfl_up(incl, off, 64);
        if (lane >= off) incl += u;
    }
    if (lane == 63) wsum[wv] = incl;
    __syncthreads();
    if (t == 0) {
        int run = 0;
#pragma unroll
        for (int i = 0; i < 16; ++i) { int v = wsum[i]; wsum[i] = run; run += v; }
    }
    __syncthreads();
    int run = wsum[wv] + incl - local;
#pragma unroll
    for (int i = 0; i < SCAN_CHUNK; ++i) {
        int idx = base + i;
        if (idx < n) {
            rowoff[idx] = run;
            cursor[idx] = run;
            dinv[idx]   = rsqrtf((float)(vals[i] + 1));
            run += vals[i];
        }
    }
    if (t == 1023) rowoff[n] = run;
    if (t < 64) {
        int s = lower_bound(batch, n, t);
        int e = lower_bound(batch, n, t + 1);
        gcinv[t] = 1.0f / (float)max(e - s, 1);
    }
}

// CSR fill + x prescale (independent, both depend only on scan)
__global__ void k_fill_prescale(const int* __restrict__ src, const int* __restrict__ dst,
                                int* __restrict__ cursor, int* __restrict__ col, int E,
                                const float* __restrict__ x, const float* __restrict__ dinv,
                                __half* __restrict__ xp, int total4) {
    int i = blockIdx.x * 256 + threadIdx.x;
    if (i < E) {
        int pos = atomicAdd(&cursor[dst[i]], 1);
        col[pos] = src[i];
    }
    if (i < total4) {
        float4 v = reinterpret_cast<const float4*>(x)[i];
        float d = dinv[i >> 5];   // 32 float4 per 128-wide row
        reinterpret_cast<uint2*>(xp)[i] =
            make_uint2(f2h_pack(v.x * d, v.y * d), f2h_pack(v.z * d, v.w * d));
    }
}

// ---------------- W transpose to plain f16 [N][K] + cnt/out zeroing ----------------
__global__ void k_split_w_all(const float* __restrict__ W1, const float* __restrict__ W2,
                              const float* __restrict__ W3, __half* __restrict__ W1T,
                              __half* __restrict__ W2T, __half* __restrict__ W3T,
                              int* __restrict__ cnt, int n,
                              float* __restrict__ out, int outsz) {
    int e = blockIdx.x * 256 + threadIdx.x;
    if (e < n) cnt[e] = 0;
    if (e < outsz) out[e] = 0.f;   // pool accumulates via atomics; re-zero every call
    if (e < 128 * 256) {
        int k = e >> 8, nn = e & 255;
        W1T[(size_t)nn * 128 + k] = __float2half(W1[e]);
    } else if (e < 128 * 256 + 256 * 256) {
        int e2 = e - 128 * 256;
        int k = e2 >> 8, nn = e2 & 255;
        W2T[(size_t)nn * 256 + k] = __float2half(W2[e2]);
    } else if (e < 128 * 256 + 256 * 256 + 256 * 64) {
        int e3 = e - 128 * 256 - 256 * 256;
        int k = e3 >> 6, nn = e3 & 63;
        W3T[(size_t)nn * 256 + k] = __float2half(W3[e3]);
    }
}

// ---------------- MFMA f16 GEMM: plain f16 A and W (1 MFMA per frag pair) ----------------
template<bool HAS_BIAS, bool RELU, bool SCALE>
__global__ __launch_bounds__(256)
void k_gemm_f16(const __half* __restrict__ Ah, const __half* __restrict__ WTh,
                const float* __restrict__ bias, const float* __restrict__ dscale,
                __half* __restrict__ Cout, int M, int K, int N) {
    __shared__ __align__(16) _Float16 Ash[64][72];
    __shared__ __align__(16) _Float16 Bsh[64][72];
    const int tid = threadIdx.x;
    const int bm = blockIdx.y * 64, bn = blockIdx.x * 64;
    const int lane = tid & 63, w = tid >> 6;
    const int wm = (w >> 1) * 32, wn = (w & 1) * 32;
    const int m_st = tid >> 2, kq = tid & 3;

    f32x4 acc[2][2];
#pragma unroll
    for (int i = 0; i < 2; ++i)
#pragma unroll
        for (int j = 0; j < 2; ++j) acc[i][j] = (f32x4){0.f, 0.f, 0.f, 0.f};

    for (int k0 = 0; k0 < K; k0 += 32) {
        {   // A tile: 16B direct copy
            int row = bm + m_st;
            uint4 u = {0, 0, 0, 0};
            if (row < M)
                u = *reinterpret_cast<const uint4*>(&Ah[(size_t)row * K + k0 + kq * 8]);
            *reinterpret_cast<uint4*>(&Ash[m_st][kq * 8]) = u;
        }
        {   // B tile: 16B direct copy (plain f16, no unpack)
            int nrow = bn + m_st;
            uint4 u = *reinterpret_cast<const uint4*>(&WTh[(size_t)nrow * K + k0 + kq * 8]);
            *reinterpret_cast<uint4*>(&Bsh[m_st][kq * 8]) = u;
        }
        __syncthreads();

        half8v a[2], b[2];
#pragma unroll
        for (int mi = 0; mi < 2; ++mi)
            a[mi] = *reinterpret_cast<const half8v*>(&Ash[wm + mi * 16 + (lane & 15)][(lane >> 4) * 8]);
#pragma unroll
        for (int ni = 0; ni < 2; ++ni)
            b[ni] = *reinterpret_cast<const half8v*>(&Bsh[wn + ni * 16 + (lane & 15)][(lane >> 4) * 8]);
#pragma unroll
        for (int mi = 0; mi < 2; ++mi)
#pragma unroll
            for (int ni = 0; ni < 2; ++ni)
                acc[mi][ni] = __builtin_amdgcn_mfma_f32_16x16x32_f16(a[mi], b[ni], acc[mi][ni], 0, 0, 0);
        __syncthreads();
    }

    // epilogue: D row=(lane>>4)*4+j, col=lane&15 (verified C/D mapping)
#pragma unroll
    for (int mi = 0; mi < 2; ++mi)
#pragma unroll
        for (int ni = 0; ni < 2; ++ni) {
            int colg = bn + wn + ni * 16 + (lane & 15);
            int rowb = bm + wm + mi * 16 + ((lane >> 4) << 2);
            float bv = 0.f;
            if constexpr (HAS_BIAS) bv = bias[colg];
#pragma unroll
            for (int j = 0; j < 4; ++j) {
                int row = rowb + j;
                if (row < M) {
                    float v = acc[mi][ni][j] + bv;
                    if constexpr (RELU) v = fmaxf(v, 0.f);
                    if constexpr (SCALE) v *= dscale[row];
                    Cout[(size_t)row * N + colg] = __float2half(v);
                }
            }
        }
}

// ---------------- Aggregate: fp16 in, 8 banks (deeper MLP), fp16 out ----------------
template<int F>
__global__ void k_aggregate(const __half* __restrict__ h,
                            const float* __restrict__ dinv, const int* __restrict__ rowoff,
                            const int* __restrict__ col, unsigned* __restrict__ out, int n) {
    constexpr int VEC = F / 64;
    int lane = threadIdx.x & 63;
    int wid  = threadIdx.x >> 6;
    int node = blockIdx.x * 4 + wid;
    if (node >= n) return;
    float di = dinv[node];
    float acc[8][VEC];
#pragma unroll
    for (int b = 0; b < 8; ++b)
#pragma unroll
        for (int v = 0; v < VEC; ++v) acc[b][v] = 0.f;
    {   // self row into bank 0
        const __half* ps = &h[(size_t)node * F + lane * VEC];
        if constexpr (VEC == 4) {
            uint2 u = *reinterpret_cast<const uint2*>(ps);
            acc[0][0] = h2f_lo(u.x); acc[0][1] = h2f_hi(u.x);
            acc[0][2] = h2f_lo(u.y); acc[0][3] = h2f_hi(u.y);
        } else {
            unsigned u = *reinterpret_cast<const unsigned*>(ps);
            acc[0][0] = h2f_lo(u); acc[0][1] = h2f_hi(u);
        }
    }
    int e = rowoff[node], s1 = rowoff[node + 1];
    for (; e + 7 < s1; e += 8) {
#pragma unroll
        for (int b = 0; b < 8; ++b) {
            int s = col[e + b];
            const __half* ps = &h[(size_t)s * F + lane * VEC];
            if constexpr (VEC == 4) {
                uint2 u = *reinterpret_cast<const uint2*>(ps);
                acc[b][0] += h2f_lo(u.x); acc[b][1] += h2f_hi(u.x);
                acc[b][2] += h2f_lo(u.y); acc[b][3] += h2f_hi(u.y);
            } else {
                unsigned u = *reinterpret_cast<const unsigned*>(ps);
                acc[b][0] += h2f_lo(u); acc[b][1] += h2f_hi(u);
            }
        }
    }
    for (; e < s1; ++e) {
        int s = col[e];
        const __half* ps = &h[(size_t)s * F + lane * VEC];
        if constexpr (VEC == 4) {
            uint2 u = *reinterpret_cast<const uint2*>(ps);
            acc[0][0] += h2f_lo(u.x); acc[0][1] += h2f_hi(u.x);
            acc[0][2] += h2f_lo(u.y); acc[0][3] += h2f_hi(u.y);
        } else {
            unsigned u = *reinterpret_cast<const unsigned*>(ps);
            acc[0][0] += h2f_lo(u); acc[0][1] += h2f_hi(u);
        }
    }

    float r[VEC];
#pragma unroll
    for (int v = 0; v < VEC; ++v)
        r[v] = ((((acc[0][v] + acc[1][v]) + (acc[2][v] + acc[3][v])) +
                 ((acc[4][v] + acc[5][v]) + (acc[6][v] + acc[7][v])))) * di;

    if constexpr (VEC == 4)
        *reinterpret_cast<uint2*>(&out[(size_t)node * 2 * 64 + lane * 2]) =
            make_uint2(f2h_pack(r[0], r[1]), f2h_pack(r[2], r[3]));
    else
        out[(size_t)node * 64 + lane] = f2h_pack(r[0], r[1]);
}

// ---------------- Layer-3 aggregate + mean-pool via per-graph atomics ----------------
__global__ void k_agg64_pool(const __half* __restrict__ h, const float* __restrict__ bias,
                             const float* __restrict__ dinv, const int* __restrict__ rowoff,
                             const int* __restrict__ col, const int* __restrict__ batch,
                             const float* __restrict__ gcinv, float* __restrict__ out, int n) {
    int lane = threadIdx.x & 63;
    int wid  = threadIdx.x >> 6;
    int node = blockIdx.x * 4 + wid;
    if (node >= n) return;
    float di = dinv[node];
    float acc[8] = {0.f, 0.f, 0.f, 0.f, 0.f, 0.f, 0.f, 0.f};
    acc[0] = __half2float(h[(size_t)node * 64 + lane]);
    int e = rowoff[node], s1 = rowoff[node + 1];
    for (; e + 7 < s1; e += 8) {
#pragma unroll
        for (int b = 0; b < 8; ++b)
            acc[b] += __half2float(h[(size_t)col[e + b] * 64 + lane]);
    }
    for (; e < s1; ++e)
        acc[0] += __half2float(h[(size_t)col[e] * 64 + lane]);
    float r = (((acc[0] + acc[1]) + (acc[2] + acc[3])) +
               ((acc[4] + acc[5]) + (acc[6] + acc[7]))) * di + bias[lane];
    int g = batch[node];
    atomicAdd(&out[g * 64 + lane], r * gcinv[g]);
}

// ---------------- Launch ----------------
extern "C" void kernel_launch(void* const* d_in, const int* in_sizes, int n_in,
                              void* d_out, int out_size, void* d_ws, size_t ws_size,
                              hipStream_t stream) {
    const float* x  = (const float*)d_in[0];
    const int* ei   = (const int*)d_in[1];
    const int* batch = (const int*)d_in[2];
    const float* W1 = (const float*)d_in[3]; const float* b1 = (const float*)d_in[4];
    const float* W2 = (const float*)d_in[5]; const float* b2 = (const float*)d_in[6];
    const float* W3 = (const float*)d_in[7]; const float* b3 = (const float*)d_in[8];
    float* out = (float*)d_out;

    const int n = in_sizes[0] / 128;
    const int E = in_sizes[1] / 2;
    const int* src = ei;
    const int* dst = ei + E;

    char* p = (char*)d_ws;
    auto carve = [&](size_t bytes) { char* q = p; p += (bytes + 255) & ~255ULL; return q; };
    char* R1      = carve((size_t)n * 256 * 4);
    char* R2      = carve((size_t)n * 256 * 4);
    float* dinv   = (float*)carve((size_t)n * 4);
    int*   cnt    = (int*)carve((size_t)n * 4);
    int*   rowoff = (int*)carve((size_t)(n + 1) * 4);
    int*   cursor = (int*)carve((size_t)n * 4);
    int*   col    = (int*)carve((size_t)E * 4);
    float* gcinv  = (float*)carve(64 * 4);
    __half* W1T   = (__half*)carve((size_t)256 * 128 * 2);
    __half* W2T   = (__half*)carve((size_t)256 * 256 * 2);
    __half* W3T   = (__half*)carve((size_t)64 * 256 * 2);

    // region aliases (lifetimes disjoint):
    __half*   XPh = (__half*)R2;     // fp16(dinv.*x) [n][128]
    unsigned* A0  = (unsigned*)R1;   // agg0 out fp16-pairs [n][128]
    __half*   H1  = (__half*)R2;     // gemm1 out (scaled) fp16 [n][256] (XPh dead)
    unsigned* A1  = (unsigned*)R1;   // agg1 out fp16-pairs [n][256] (A0 dead)
    __half*   P2  = (__half*)R2;     // gemm2 out fp16 [n][256] (H1 dead)
    __half*   T3  = (__half*)R1;     // gemm3 out (scaled) fp16 [n][64] (A1 dead)

    // 1: W transpose to f16 + cnt zero + d_out zero
    k_split_w_all<<<(128*256 + 256*256 + 256*64 + 255) / 256, 256, 0, stream>>>(
        W1, W2, W3, W1T, W2T, W3T, cnt, n, out, out_size);
    // 2: degree count
    k_count<<<(E + 255) / 256, 256, 0, stream>>>(dst, cnt, E);
    // 3: scan -> rowoff/cursor/dinv + gcinv
    k_scan<<<1, 1024, 0, stream>>>(cnt, rowoff, cursor, dinv, n, batch, gcinv);
    // 4: CSR fill + x prescale (fused)
    {
        int total4 = n * 32;
        int mx = total4 > E ? total4 : E;
        k_fill_prescale<<<(mx + 255) / 256, 256, 0, stream>>>(
            src, dst, cursor, col, E, x, dinv, XPh, total4);
    }
    const int mblocks = (n + 63) / 64;
    // 5: agg0 = fp16(dinv.*(gather-sum XPh))
    k_aggregate<128><<<(n + 3) / 4, 256, 0, stream>>>(
        XPh, dinv, rowoff, col, A0, n);
    // 6: H1 = fp16( relu(A0@W1+b1) .* dinv )
    k_gemm_f16<true, true, true><<<dim3(4, mblocks), 256, 0, stream>>>(
        (const __half*)A0, W1T, b1, dinv, H1, n, 128, 256);
    // 7: agg1 = fp16(dinv.*(gather-sum H1))
    k_aggregate<256><<<(n + 3) / 4, 256, 0, stream>>>(
        H1, dinv, rowoff, col, A1, n);
    // 8: P2 = fp16(relu(A1@W2+b2))
    k_gemm_f16<true, true, false><<<dim3(4, mblocks), 256, 0, stream>>>(
        (const __half*)A1, W2T, b2, nullptr, P2, n, 256, 256);
    // 9: T3 = fp16( (P2@W3) .* dinv )
    k_gemm_f16<false, false, true><<<dim3(1, mblocks), 256, 0, stream>>>(
        P2, W3T, nullptr, dinv, T3, n, 256, 64);
    // 10: layer-3 aggregate + mean pool (atomic)
    k_agg64_pool<<<(n + 3) / 4, 256, 0, stream>>>(
        T3, b3, dinv, rowoff, col, batch, gcinv, out, n);
}